// Round 7
// baseline (704.577 us; speedup 1.0000x reference)
//
#include <hip/hip_runtime.h>
#include <math.h>

#define C      256
#define NPIX   196
#define BATCH  64
#define MAT    65536                  // C*C
#define PL     4194304                // BATCH*MAT (one bf16 plane, elements)
#define OUTPB  32896                  // C*(C+1)/2

typedef short s16x8 __attribute__((ext_vector_type(8)));
typedef float f32x4 __attribute__((ext_vector_type(4)));

// ---- bf16 split helpers (RNE) ---------------------------------------------
__device__ __forceinline__ short bfhi(float v) {
    unsigned int u = __float_as_uint(v);
    u = (u + 0x7fffu + ((u >> 16) & 1u)) >> 16;
    return (short)u;
}
__device__ __forceinline__ float bff(short h) {
    return __uint_as_float(((unsigned int)(unsigned short)h) << 16);
}
__device__ __forceinline__ void bfsplit(float v, short& h, short& l) {
    h = bfhi(v);
    l = bfhi(v - bff(h));
}

// ---------------------------------------------------------------------------
__global__ __launch_bounds__(256) void zero_k(unsigned int* __restrict__ c) {
    c[blockIdx.x * 256 + threadIdx.x] = 0u;   // grid 4 -> 1024 uints
}

// ---------------------------------------------------------------------------
// convert: row-mean centering, bf16 hi/lo split, zero-pad K 196->256.
// XCD-pinned so batch b's xc lands hot in L2 of XCD b%8.
// ---------------------------------------------------------------------------
__global__ __launch_bounds__(256) void convert_k(const float* __restrict__ x,
                                                 short* __restrict__ xc,
                                                 float* __restrict__ rowsq) {
    const int bid = blockIdx.x;               // 4096 blocks
    const int xcd = bid & 7, j = bid >> 3;
    const int lb = j & 7, rc = j >> 3;
    const int b = xcd + (lb << 3);
    const int wave = threadIdx.x >> 6, lane = threadIdx.x & 63;
    const int row = rc * 4 + wave;
    const int rowg = b * 256 + row;
    const float* xr = x + (size_t)rowg * NPIX;
    float v[4];
    #pragma unroll
    for (int i = 0; i < 4; ++i) {
        int c = lane + (i << 6);
        v[i] = (c < NPIX) ? xr[c] : 0.f;
    }
    float s = v[0] + v[1] + v[2] + v[3];
    #pragma unroll
    for (int off = 32; off; off >>= 1) s += __shfl_xor(s, off, 64);
    const float mean = s * (1.f / NPIX);

    short* oh = xc + (size_t)b * MAT + (size_t)row * C;
    short* ol = oh + PL;
    float sq = 0.f;
    #pragma unroll
    for (int i = 0; i < 4; ++i) {
        int c = lane + (i << 6);
        float w = (c < NPIX) ? (v[i] - mean) : 0.f;
        sq += w * w;
        short h, l;
        bfsplit(w, h, l);
        oh[c] = h;
        ol[c] = l;
    }
    #pragma unroll
    for (int off = 32; off; off >>= 1) sq += __shfl_xor(sq, off, 64);
    if (lane == 0) rowsq[rowg] = sq;
}

// ---------------------------------------------------------------------------
__global__ __launch_bounds__(256) void tracered_k(const float* __restrict__ rowsq,
                                                  float* __restrict__ trsum) {
    const int b = blockIdx.x, t = threadIdx.x;
    float v = rowsq[b * 256 + t];
    __shared__ float red[4];
    #pragma unroll
    for (int off = 32; off; off >>= 1) v += __shfl_xor(v, off, 64);
    if ((t & 63) == 0) red[t >> 6] = v;
    __syncthreads();
    if (t == 0) trsum[b] = red[0] + red[1] + red[2] + red[3];
}

// ---------------------------------------------------------------------------
// 16-member stream barrier (flags in the stream's XCD L2). Release add
// publishes prior stores; acquire agent fence invalidates stale L1 lines.
// ---------------------------------------------------------------------------
__device__ __forceinline__ void xbar(unsigned int* c) {
    __syncthreads();
    if (threadIdx.x == 0) {
        __hip_atomic_fetch_add(c, 1u, __ATOMIC_RELEASE, __HIP_MEMORY_SCOPE_AGENT);
        while (__hip_atomic_load(c, __ATOMIC_RELAXED, __HIP_MEMORY_SCOPE_AGENT) < 16u) {}
        __builtin_amdgcn_fence(__ATOMIC_ACQUIRE, "agent");
    }
    __syncthreads();
}

__device__ __forceinline__ void wsplit(short* __restrict__ base, int r, int c, float v) {
    short h, l;
    bfsplit(v, h, l);
    base[(size_t)r * C + c] = h;
    base[PL + (size_t)r * C + c] = l;
}

// ---------------------------------------------------------------------------
// One 64x64 output tile (i,j) of a 256x256 split-bf16 matmul step.
// SINGLE noinline copy (20 inlined instantiations segfaulted clang in r6).
// 4 waves (2x2), wave tile 32x32 via 2x2 mfma_f32_16x16x32_bf16, 3-term split.
// Operand fragments use identical addressing (all chain matrices symmetric).
// mode 0: o0 = A@B        mode 1: o0 = 1.5I - 0.5 A@B
// mode 2: outfb = triu_packed(A@B * sqrt(ts/n))
// mode 3: o0 = A@B/ts ; o1 = 1.5I - 0.5*o0
// mode 4: o0 = A@B ; o1 = A2@B  (shared staged B panel)
// ---------------------------------------------------------------------------
__device__ __noinline__ void mm_step_rt(int mode,
                                        const short* __restrict__ Ap,
                                        const short* __restrict__ A2p,
                                        const short* __restrict__ Bp,
                                        short* __restrict__ o0,
                                        short* __restrict__ o1,
                                        float* __restrict__ outfb,
                                        int i, int j, float ts) {
    __shared__ __align__(16) short lds[24576];   // 48 KB, reused across calls
    const int t = threadIdx.x;
    const int lane = t & 63, wid = t >> 6;
    const int wr = wid >> 1, wc = wid & 1;
    const int lr = lane & 15, lg = lane >> 4;
    const bool pair = (mode == 4);
    const int nch = pair ? 12 : 8;

    f32x4 acc[2][2], acc2[2][2];
    const f32x4 zero = {0.f, 0.f, 0.f, 0.f};
    #pragma unroll
    for (int a = 0; a < 2; ++a)
        #pragma unroll
        for (int bb = 0; bb < 2; ++bb) { acc[a][bb] = zero; acc2[a][bb] = zero; }

    for (int k0 = 0; k0 < C; k0 += 64) {
        for (int cidx = 0; cidx < nch; ++cidx) {
            const int u = cidx * 256 + t;
            const int sec = u >> 9;               // 0,1:A-hi/lo 2,3:B 4,5:A2
            const int rr = (u >> 3) & 63, ch = u & 7;
            const short* src =
                (sec == 0) ? Ap  +      (size_t)(i * 64 + rr) * C :
                (sec == 1) ? Ap  + PL + (size_t)(i * 64 + rr) * C :
                (sec == 2) ? Bp  +      (size_t)(j * 64 + rr) * C :
                (sec == 3) ? Bp  + PL + (size_t)(j * 64 + rr) * C :
                (sec == 4) ? A2p +      (size_t)(i * 64 + rr) * C :
                             A2p + PL + (size_t)(i * 64 + rr) * C;
            s16x8 v = *(const s16x8*)(src + k0 + ch * 8);
            *(s16x8*)&lds[sec * 4096 + rr * 64 + ((ch ^ (rr & 7)) << 3)] = v;
        }
        __syncthreads();
        #pragma unroll
        for (int kk = 0; kk < 64; kk += 32) {
            s16x8 ah[2], al[2], bh[2], bl[2];
            #pragma unroll
            for (int f = 0; f < 2; ++f) {
                const int ra = wr * 32 + f * 16 + lr;
                const int ca = ((kk >> 3) + lg) ^ (ra & 7);
                ah[f] = *(const s16x8*)&lds[0 * 4096 + ra * 64 + (ca << 3)];
                al[f] = *(const s16x8*)&lds[1 * 4096 + ra * 64 + (ca << 3)];
                const int rb = wc * 32 + f * 16 + lr;
                const int cb = ((kk >> 3) + lg) ^ (rb & 7);
                bh[f] = *(const s16x8*)&lds[2 * 4096 + rb * 64 + (cb << 3)];
                bl[f] = *(const s16x8*)&lds[3 * 4096 + rb * 64 + (cb << 3)];
            }
            #pragma unroll
            for (int fi = 0; fi < 2; ++fi)
                #pragma unroll
                for (int fj = 0; fj < 2; ++fj) {
                    acc[fi][fj] = __builtin_amdgcn_mfma_f32_16x16x32_bf16(ah[fi], bh[fj], acc[fi][fj], 0, 0, 0);
                    acc[fi][fj] = __builtin_amdgcn_mfma_f32_16x16x32_bf16(ah[fi], bl[fj], acc[fi][fj], 0, 0, 0);
                    acc[fi][fj] = __builtin_amdgcn_mfma_f32_16x16x32_bf16(al[fi], bh[fj], acc[fi][fj], 0, 0, 0);
                }
            if (pair) {
                s16x8 a2h[2], a2l[2];
                #pragma unroll
                for (int f = 0; f < 2; ++f) {
                    const int ra = wr * 32 + f * 16 + lr;
                    const int ca = ((kk >> 3) + lg) ^ (ra & 7);
                    a2h[f] = *(const s16x8*)&lds[4 * 4096 + ra * 64 + (ca << 3)];
                    a2l[f] = *(const s16x8*)&lds[5 * 4096 + ra * 64 + (ca << 3)];
                }
                #pragma unroll
                for (int fi = 0; fi < 2; ++fi)
                    #pragma unroll
                    for (int fj = 0; fj < 2; ++fj) {
                        acc2[fi][fj] = __builtin_amdgcn_mfma_f32_16x16x32_bf16(a2h[fi], bh[fj], acc2[fi][fj], 0, 0, 0);
                        acc2[fi][fj] = __builtin_amdgcn_mfma_f32_16x16x32_bf16(a2h[fi], bl[fj], acc2[fi][fj], 0, 0, 0);
                        acc2[fi][fj] = __builtin_amdgcn_mfma_f32_16x16x32_bf16(a2l[fi], bh[fj], acc2[fi][fj], 0, 0, 0);
                    }
            }
        }
        __syncthreads();
    }

    const float invT  = 1.f / ts;
    const float scale = sqrtf(ts * (1.f / NPIX));
    #pragma unroll
    for (int fi = 0; fi < 2; ++fi)
        #pragma unroll
        for (int fj = 0; fj < 2; ++fj)
            #pragma unroll
            for (int q = 0; q < 4; ++q) {
                const int r_t = i * 64 + wr * 32 + fi * 16 + lg * 4 + q;
                const int c_t = j * 64 + wc * 32 + fj * 16 + lr;
                const float v = acc[fi][fj][q];
                if (mode == 0) {
                    wsplit(o0, r_t, c_t, v);
                } else if (mode == 1) {
                    wsplit(o0, r_t, c_t, ((r_t == c_t) ? 1.5f : 0.f) - 0.5f * v);
                } else if (mode == 3) {
                    const float a = v * invT;
                    wsplit(o0, r_t, c_t, a);
                    wsplit(o1, r_t, c_t, ((r_t == c_t) ? 1.5f : 0.f) - 0.5f * a);
                } else if (mode == 4) {
                    wsplit(o0, r_t, c_t, v);
                    wsplit(o1, r_t, c_t, acc2[fi][fj][q]);
                } else {   // mode 2
                    if (c_t >= r_t) {
                        const int off = r_t * C - (r_t * (r_t - 1)) / 2 - r_t + c_t;
                        outfb[off] = v * scale;
                    }
                }
            }
}

// ---------------------------------------------------------------------------
// Persistent chain kernel: 512 blocks = 2/CU (48KB LDS). 32 streams of 16
// members; stream (xcd, sl) processes batches b = xcd + 8*(2*sl + it) so each
// batch's entire NS chain stays in its XCD's L2. Member m owns tile (m>>2,m&3).
// Step table: mode / A / A2 / B / out0 / out1 over buffers {b0..b4}.
// ---------------------------------------------------------------------------
__global__ __launch_bounds__(256, 2) void persist_k(short* __restrict__ b0,
                                                    short* __restrict__ b1,
                                                    short* __restrict__ b2,
                                                    short* __restrict__ b3,
                                                    short* __restrict__ b4,
                                                    const float* __restrict__ trsum,
                                                    float* __restrict__ outf,
                                                    unsigned int* __restrict__ cnt) {
    const int bid = blockIdx.x;
    const int xcd = bid & 7;
    const int k = bid >> 3;                      // [0,64)
    const int sl = k & 3;                        // stream-in-xcd
    const int m = k >> 2;                        // member [0,16)
    const int i = m >> 2, j = m & 3;
    unsigned int* scnt = cnt + (xcd * 4 + sl) * 32;
    int phase = 0;

    static const signed char MD[10]  = {3, 0, 1, 4, 1, 4, 1, 4, 1, 2};
    static const signed char SA[10]  = {4, 0, 1, 2, 4, 0, 3, 2, 1, 4};
    static const signed char SA2[10] = {0, 0, 0, 1, 0, 4, 0, 3, 0, 0};
    static const signed char SB[10]  = {4, 1, 2, 3, 0, 1, 2, 0, 4, 2};
    static const signed char SO0[10] = {0, 2, 3, 0, 1, 2, 0, 4, 2, 0};
    static const signed char SO1[10] = {1, 0, 0, 4, 0, 3, 0, 1, 0, 0};

    for (int it = 0; it < 2; ++it) {
        const int b = xcd + 8 * (sl * 2 + it);
        const size_t mb = (size_t)b * MAT;
        const float ts = trsum[b];
        short* P[5] = {b0 + mb, b1 + mb, b2 + mb, b3 + mb, b4 + mb};

        for (int s = 0; s < 10; ++s) {
            const int md = MD[s];
            if (md == 2) {
                if (i <= j)
                    mm_step_rt(2, P[SA[s]], nullptr, P[SB[s]], nullptr, nullptr,
                               outf + (size_t)b * OUTPB, i, j, ts);
            } else {
                mm_step_rt(md, P[SA[s]], P[SA2[s]], P[SB[s]], P[SO0[s]], P[SO1[s]],
                           nullptr, i, j, ts);
                xbar(&scnt[phase++]);
            }
        }
    }
}

// ---------------------------------------------------------------------------
extern "C" void kernel_launch(void* const* d_in, const int* in_sizes, int n_in,
                              void* d_out, int out_size, void* d_ws, size_t ws_size,
                              hipStream_t stream) {
    const float* x = (const float*)d_in[0];
    float* out = (float*)d_out;
    short* base = (short*)d_ws;
    short* b0 = base;
    short* b1 = base + (size_t)2 * PL;
    short* b2 = base + (size_t)4 * PL;
    short* b3 = base + (size_t)6 * PL;
    short* b4 = base + (size_t)8 * PL;   // doubles as xc
    float* trsum = (float*)(base + (size_t)10 * PL);
    float* rowsq = trsum + 256;
    unsigned int* cnt = (unsigned int*)(rowsq + BATCH * C);

    dim3 blk(256);
    zero_k<<<dim3(4), blk, 0, stream>>>(cnt);
    convert_k<<<dim3(4096), blk, 0, stream>>>(x, b4, rowsq);
    tracered_k<<<dim3(64), blk, 0, stream>>>(rowsq, trsum);
    persist_k<<<dim3(512), blk, 0, stream>>>(b0, b1, b2, b3, b4, trsum, out, cnt);
}

// Round 8
// 151.537 us; speedup vs baseline: 4.6495x; 4.6495x over previous
//
#include <hip/hip_runtime.h>
#include <math.h>

#define C      256
#define NPIX   196
#define BATCH  64
#define MAT    65536                  // C*C
#define PLH    4194304                // BATCH*MAT (one fp16 plane, elements)
#define OUTPB  32896                  // C*(C+1)/2

typedef _Float16 f16x8 __attribute__((ext_vector_type(8)));
typedef float    f32x4 __attribute__((ext_vector_type(4)));

// ---------------------------------------------------------------------------
// convert: row-mean centering -> fp16, zero-pad K 196->256, per-row sum(xc^2).
// XCD-pinned: batch b on XCD b%8.
// ---------------------------------------------------------------------------
__global__ __launch_bounds__(256) void convert_k(const float* __restrict__ x,
                                                 _Float16* __restrict__ xc,
                                                 float* __restrict__ rowsq) {
    const int bid = blockIdx.x;               // 4096 blocks
    const int xcd = bid & 7, j = bid >> 3;
    const int lb = j & 7, rc = j >> 3;
    const int b = xcd + (lb << 3);
    const int wave = threadIdx.x >> 6, lane = threadIdx.x & 63;
    const int row = rc * 4 + wave;
    const int rowg = b * 256 + row;
    const float* xr = x + (size_t)rowg * NPIX;
    float v[4];
    #pragma unroll
    for (int i = 0; i < 4; ++i) {
        int c = lane + (i << 6);
        v[i] = (c < NPIX) ? xr[c] : 0.f;
    }
    float s = v[0] + v[1] + v[2] + v[3];
    #pragma unroll
    for (int off = 32; off; off >>= 1) s += __shfl_xor(s, off, 64);
    const float mean = s * (1.f / NPIX);

    _Float16* o = xc + (size_t)b * MAT + (size_t)row * C;
    float sq = 0.f;
    #pragma unroll
    for (int i = 0; i < 4; ++i) {
        int c = lane + (i << 6);
        float w = (c < NPIX) ? (v[i] - mean) : 0.f;
        sq += w * w;
        o[c] = (_Float16)w;
    }
    #pragma unroll
    for (int off = 32; off; off >>= 1) sq += __shfl_xor(sq, off, 64);
    if (lane == 0) rowsq[rowg] = sq;
}

// ---------------------------------------------------------------------------
__global__ __launch_bounds__(256) void tracered_k(const float* __restrict__ rowsq,
                                                  float* __restrict__ trsum) {
    const int b = blockIdx.x, t = threadIdx.x;
    float v = rowsq[b * 256 + t];
    __shared__ float red[4];
    #pragma unroll
    for (int off = 32; off; off >>= 1) v += __shfl_xor(v, off, 64);
    if ((t & 63) == 0) red[t >> 6] = v;
    __syncthreads();
    if (t == 0) trsum[b] = red[0] + red[1] + red[2] + red[3];
}

// ---------------------------------------------------------------------------
// Batched 256x256x256 fp16 MFMA matmul, tile BM=64 x BN=128.
// XCD-pinned flat grid: singles 512 blocks, pair 1024.
// 4 waves (2x2), wave tile 32x64 via 2x4 mfma_f32_16x16x32_f16.
// Operand fragments use identical addressing (all matrices symmetric; the
// gram is xc@xc^T which is exactly the row-panel product).
// MODE 0: o0 = A@B          MODE 1: o0 = 1.5I - 0.5 A@B
// MODE 2: outf = triu_packed(A@B * sqrt(ts/n))
// MODE 3: o0 = A@B/ts ; o1 = 1.5I - 0.5*o0
// MODE 4: pair — half 0: o0 = A0@B ; half 1: o1 = A1@B
// ---------------------------------------------------------------------------
template <int MODE>
__global__ __launch_bounds__(256) void mm_k(const _Float16* __restrict__ A0,
                                            const _Float16* __restrict__ A1,
                                            const _Float16* __restrict__ Bop,
                                            _Float16* __restrict__ o0,
                                            _Float16* __restrict__ o1,
                                            float* __restrict__ outf,
                                            const float* __restrict__ trsum) {
    const int bid = blockIdx.x;
    const int xcd = bid & 7, j = bid >> 3;
    const int t8 = j & 7;
    const int bm = t8 >> 1, bn = t8 & 1;
    const int q = j >> 3;
    const int half = (MODE == 4) ? (q >> 3) : 0;
    const int b = xcd + ((q & 7) << 3);
    if (MODE == 2 && bn == 0 && bm >= 2) return;   // fully strictly-lower tile

    __shared__ __align__(16) _Float16 lds[16384];  // A:4096  B:8192  A2:4096

    const int t = threadIdx.x;
    const int lane = t & 63, wid = t >> 6;
    const int wr = wid >> 1, wc = wid & 1;
    const int lr = lane & 15, lg = lane >> 4;

    const size_t mb = (size_t)b * MAT;
    const _Float16* Ap = ((MODE == 4 && half) ? A1 : A0) + mb;
    const _Float16* A2p = (MODE == 4) ? (A1 + mb) : nullptr;  // unused unless pair
    const _Float16* Bp = Bop + mb;
    const int rowA0 = bm * 64, rowB0 = bn * 128;
    (void)A2p;

    f32x4 acc[2][4];
    const f32x4 zero = {0.f, 0.f, 0.f, 0.f};
    #pragma unroll
    for (int i = 0; i < 2; ++i)
        #pragma unroll
        for (int jj = 0; jj < 4; ++jj) acc[i][jj] = zero;

    for (int k0 = 0; k0 < C; k0 += 64) {
        // stage: A 512 chunks (cidx 0-1), B 1024 chunks (cidx 2-5), 16B each
        #pragma unroll
        for (int cidx = 0; cidx < 6; ++cidx) {
            const int u = cidx * 256 + t;
            int rr, ch, dstbase;
            const _Float16* src;
            if (u < 512) {
                rr = u >> 3; ch = u & 7;
                src = Ap + (size_t)(rowA0 + rr) * C;
                dstbase = 0;
            } else {
                const int v2 = u - 512;
                rr = v2 >> 3; ch = v2 & 7;
                src = Bp + (size_t)(rowB0 + rr) * C;
                dstbase = 4096;
            }
            f16x8 v = *(const f16x8*)(src + k0 + ch * 8);
            *(f16x8*)&lds[dstbase + rr * 64 + ((ch ^ (rr & 7)) << 3)] = v;
        }
        __syncthreads();
        #pragma unroll
        for (int kk = 0; kk < 64; kk += 32) {
            f16x8 av[2], bv[4];
            #pragma unroll
            for (int f = 0; f < 2; ++f) {
                const int ra = wr * 32 + f * 16 + lr;
                const int ca = ((kk >> 3) + lg) ^ (ra & 7);
                av[f] = *(const f16x8*)&lds[ra * 64 + (ca << 3)];
            }
            #pragma unroll
            for (int f = 0; f < 4; ++f) {
                const int rb = wc * 64 + f * 16 + lr;
                const int cb = ((kk >> 3) + lg) ^ (rb & 7);
                bv[f] = *(const f16x8*)&lds[4096 + rb * 64 + (cb << 3)];
            }
            #pragma unroll
            for (int fi = 0; fi < 2; ++fi)
                #pragma unroll
                for (int fj = 0; fj < 4; ++fj)
                    acc[fi][fj] = __builtin_amdgcn_mfma_f32_16x16x32_f16(av[fi], bv[fj], acc[fi][fj], 0, 0, 0);
        }
        __syncthreads();
    }

    // ---- epilogue ----
    float ts = 0.f;
    if (MODE == 2 || MODE == 3) ts = trsum[b];
    const float invT  = (MODE == 3) ? (1.f / ts) : 0.f;
    const float scale = (MODE == 2) ? sqrtf(ts * (1.f / NPIX)) : 0.f;
    _Float16* dst = (MODE == 4 && half) ? o1 : o0;

    #pragma unroll
    for (int fi = 0; fi < 2; ++fi) {
        #pragma unroll
        for (int fj = 0; fj < 4; ++fj) {
            #pragma unroll
            for (int qq = 0; qq < 4; ++qq) {
                const int r_t = bm * 64 + wr * 32 + fi * 16 + lg * 4 + qq;
                const int c_t = bn * 128 + wc * 64 + fj * 16 + lr;
                const float v = acc[fi][fj][qq];
                if (MODE == 0 || MODE == 4) {
                    dst[mb + (size_t)r_t * C + c_t] = (_Float16)v;
                } else if (MODE == 1) {
                    o0[mb + (size_t)r_t * C + c_t] =
                        (_Float16)(((r_t == c_t) ? 1.5f : 0.f) - 0.5f * v);
                } else if (MODE == 3) {
                    const float a = v * invT;
                    o0[mb + (size_t)r_t * C + c_t] = (_Float16)a;
                    o1[mb + (size_t)r_t * C + c_t] =
                        (_Float16)(((r_t == c_t) ? 1.5f : 0.f) - 0.5f * a);
                } else if (MODE == 2) {
                    if (c_t >= r_t) {
                        const int off = r_t * C - (r_t * (r_t - 1)) / 2 - r_t + c_t;
                        outf[(size_t)b * OUTPB + off] = v * scale;
                    }
                }
            }
        }
    }
}

// ---------------------------------------------------------------------------
extern "C" void kernel_launch(void* const* d_in, const int* in_sizes, int n_in,
                              void* d_out, int out_size, void* d_ws, size_t ws_size,
                              hipStream_t stream) {
    const float* x = (const float*)d_in[0];
    float* out = (float*)d_out;
    _Float16* base = (_Float16*)d_ws;
    _Float16* b0 = base;
    _Float16* b1 = base + (size_t)1 * PLH;
    _Float16* b2 = base + (size_t)2 * PLH;
    _Float16* b3 = base + (size_t)3 * PLH;
    _Float16* b4 = base + (size_t)4 * PLH;   // doubles as xc
    float* trsum = (float*)(base + (size_t)5 * PLH);
    float* rowsq = trsum + 256;

    dim3 blk(256);
    dim3 gS(512), gP(1024);

    // xc (centered fp16, padded) -> b4 ; rowsq ; trsum
    convert_k<<<dim3(4096), blk, 0, stream>>>(x, b4, rowsq);
    tracered_k<<<dim3(64), blk, 0, stream>>>(rowsq, trsum);
    // gram: A -> b0, Z1 -> b1
    mm_k<3><<<gS, blk, 0, stream>>>(b4, nullptr, b4, b0, b1, nullptr, trsum);
    // Y1 = A @ Z1 -> b2
    mm_k<0><<<gS, blk, 0, stream>>>(b0, nullptr, b1, b2, nullptr, nullptr, nullptr);
    // iter 1
    mm_k<1><<<gS, blk, 0, stream>>>(b1, nullptr, b2, b3, nullptr, nullptr, nullptr); // Bn1=b3
    mm_k<4><<<gP, blk, 0, stream>>>(b2, b1, b3, b0, b4, nullptr, nullptr);           // Y2->b0, Z2->b4
    // iter 2
    mm_k<1><<<gS, blk, 0, stream>>>(b4, nullptr, b0, b1, nullptr, nullptr, nullptr); // Bn2=b1
    mm_k<4><<<gP, blk, 0, stream>>>(b0, b4, b1, b2, b3, nullptr, nullptr);           // Y3->b2, Z3->b3
    // iter 3
    mm_k<1><<<gS, blk, 0, stream>>>(b3, nullptr, b2, b0, nullptr, nullptr, nullptr); // Bn3=b0
    mm_k<4><<<gP, blk, 0, stream>>>(b2, b3, b0, b4, b1, nullptr, nullptr);           // Y4->b4, Z4->b1
    // final
    mm_k<1><<<gS, blk, 0, stream>>>(b1, nullptr, b4, b2, nullptr, nullptr, nullptr); // Bf=b2
    mm_k<2><<<gS, blk, 0, stream>>>(b4, nullptr, b2, nullptr, nullptr, out, trsum);  // out
}